// Round 20
// baseline (150.055 us; speedup 1.0000x reference)
//
#include <hip/hip_runtime.h>
#include <math.h>

typedef unsigned short u16;
typedef unsigned short u16x8 __attribute__((ext_vector_type(8)));
typedef __bf16 bf16v8 __attribute__((ext_vector_type(8)));
typedef float f32x4 __attribute__((ext_vector_type(4)));

static __device__ __forceinline__ float b2f(u16 u){ union{unsigned v; float f;} x; x.v=((unsigned)u)<<16; return x.f; }
static __device__ __forceinline__ u16 f2b(float f){ union{float f; unsigned v;} x; x.f=f; unsigned r=x.v+0x7fffu+((x.v>>16)&1u); return (u16)(r>>16); }
static __device__ __forceinline__ f32x4 mfma16(bf16v8 a, bf16v8 b, f32x4 c){
  return __builtin_amdgcn_mfma_f32_16x16x32_bf16(a,b,c,0,0,0);
}
#define GLDS16(g,l) __builtin_amdgcn_global_load_lds((const __attribute__((address_space(1))) unsigned*)(g), (__attribute__((address_space(3))) unsigned*)(l), 16, 0, 0)

// ---------------- fused prep: 5 weight transposes (blk<896) + rmsnorm1 ----------------
__global__ __launch_bounds__(256) void prep_k(
    const float* __restrict__ Wqkv, const float* __restrict__ Wskv, const float* __restrict__ Wout,
    const float* __restrict__ Wff1, const float* __restrict__ Wff2,
    u16* __restrict__ Tqkv, u16* __restrict__ Tskv, u16* __restrict__ Tout,
    u16* __restrict__ Tff1, u16* __restrict__ Tff2,
    const float* __restrict__ x, const float* __restrict__ g, u16* __restrict__ o){
  __shared__ u16 tile[64][66];
  int blk = blockIdx.x, t = threadIdx.x;
  if (blk < 896){
    const float* in; u16* out; int R, C, lb;
    if (blk < 192){ in=Wqkv; out=Tqkv; R=512;  C=1536; lb=blk; }
    else if (blk < 704){ in=Wskv; out=Tskv; R=4096; C=512; lb=blk-192; }
    else if (blk < 768){ in=Wout; out=Tout; R=512; C=512; lb=blk-704; }
    else if (blk < 832){ in=Wff1; out=Tff1; R=512; C=512; lb=blk-768; }
    else { in=Wff2; out=Tff2; R=512; C=512; lb=blk-832; }
    int ct = C >> 6;
    int bx = lb % ct, by = lb / ct;
    #pragma unroll
    for (int it=0; it<16; ++it){
      int idx = it*256 + t; int r = idx>>6, c = idx&63;
      tile[r][c] = f2b(in[(size_t)(by*64+r)*C + bx*64 + c]);
    }
    __syncthreads();
    #pragma unroll
    for (int it=0; it<16; ++it){
      int idx = it*256 + t; int c = idx>>6, r = idx&63;
      out[(size_t)(bx*64+c)*R + by*64 + r] = tile[r][c];
    }
    return;
  }
  int w = t>>6, l = t&63;
  size_t row = (size_t)(blk-896)*4 + w;
  const float* xr = x + row*512 + l*8;
  f32x4 a = *(const f32x4*)xr, b = *(const f32x4*)(xr+4);
  float f[8]; float ss = 0.f;
  #pragma unroll
  for (int j=0;j<4;++j){ f[j]=a[j]; f[j+4]=b[j]; }
  #pragma unroll
  for (int j=0;j<8;++j) ss += f[j]*f[j];
  #pragma unroll
  for (int m=1;m<64;m<<=1) ss += __shfl_xor(ss, m, 64);
  float inv = rsqrtf(ss*(1.0f/512.f) + 1e-6f);
  f32x4 ga = *(const f32x4*)(g + l*8), gb = *(const f32x4*)(g + l*8 + 4);
  u16x8 ov;
  #pragma unroll
  for (int j=0;j<4;++j){ ov[j] = f2b(f[j]*inv*(1.f + ga[j])); ov[j+4] = f2b(f[j+4]*inv*(1.f + gb[j])); }
  *(u16x8*)(o + row*512 + l*8) = ov;
}

// ---------------- rmsnorm: f32 in, f32 gamma, bf16 out ----------------
__global__ __launch_bounds__(256) void rmsn_k(const float* __restrict__ x, const float* __restrict__ g, u16* __restrict__ o){
  int w = threadIdx.x>>6, l = threadIdx.x&63;
  size_t row = (size_t)blockIdx.x*4 + w;
  const float* xr = x + row*512 + l*8;
  f32x4 a = *(const f32x4*)xr, b = *(const f32x4*)(xr+4);
  float f[8]; float ss = 0.f;
  #pragma unroll
  for (int j=0;j<4;++j){ f[j]=a[j]; f[j+4]=b[j]; }
  #pragma unroll
  for (int j=0;j<8;++j) ss += f[j]*f[j];
  #pragma unroll
  for (int m=1;m<64;m<<=1) ss += __shfl_xor(ss, m, 64);
  float inv = rsqrtf(ss*(1.0f/512.f) + 1e-6f);
  f32x4 ga = *(const f32x4*)(g + l*8), gb = *(const f32x4*)(g + l*8 + 4);
  u16x8 ov;
  #pragma unroll
  for (int j=0;j<4;++j){ ov[j] = f2b(f[j]*inv*(1.f + ga[j])); ov[j+4] = f2b(f[j+4]*inv*(1.f + gb[j])); }
  *(u16x8*)(o + row*512 + l*8) = ov;
}

// ---------------- GEMM: C[M,N] = A[M,K] @ BT[N,K]^T (+epilogue or split-K partial) ----------------
// F32A (with CONCAT): A is f32 (vk/vv), staged via global_load_lds (f32 tile in LDS),
//   converted bf16 at fragment read via (__bf16) casts.
// EPI 0: bias->bf16 Cb ; 1: bias+resid->f32 Cf ; 2: bias+gelu->bf16 Cb ; 3: bias+addf->f32 Cf
// EPI 4: fused qkv epilogue (q/k: bias+RoPE -> Qhp/KEYSp; v -> Cb).
template<int BM, int BN, int EPI, bool CONCAT, bool F32A, int SPLITS, int WAVES>
__global__ __launch_bounds__(256,WAVES) void gemm_k(
  const u16* __restrict__ A, const void* __restrict__ Avk, const void* __restrict__ Avv,
  const u16* __restrict__ BT, const float* __restrict__ bias,
  u16* __restrict__ Cb, float* __restrict__ Cf,
  const float* __restrict__ resid, const float* __restrict__ addf,
  u16* __restrict__ Qhp, u16* __restrict__ KEYSp,
  int M, int N, int K)
{
  constexpr int BK = 64;
  constexpr int MFR = BM/32, NFR = BN/32;
  constexpr int ABYTES = F32A ? BM*BK*4 : BM*BK*2;
  __shared__ alignas(16) char sm[ABYTES + BN*BK*2];
  float* Asf = (float*)sm;
  u16* As = (u16*)sm;
  u16* Bs = (u16*)(sm + ABYTES);
  const int t = threadIdx.x, w = t>>6, l = t&63, grp = l>>4, l16 = l&15;
  const int wr = w>>1, wc = w&1;
  const int m0 = blockIdx.x*BM, n0 = blockIdx.y*BN;
  const int kchunk = K/SPLITS, kbeg = blockIdx.z*kchunk, kend = kbeg + kchunk;

  f32x4 acc[MFR][NFR];
  #pragma unroll
  for (int m=0;m<MFR;++m)
    #pragma unroll
    for (int n=0;n<NFR;++n) acc[m][n] = f32x4{0.f,0.f,0.f,0.f};

  for (int k0 = kbeg; k0 < kend; k0 += BK){
    if (F32A && CONCAT){
      #pragma unroll
      for (int it=0; it<BM/16; ++it){
        int p = it*256 + t;
        int row = p>>4, c16 = p&15;
        int sc = c16 ^ (row & 7);
        int gg = m0+row, bb = gg>>10, ii = gg&1023;
        const float* basef = (ii < 512) ? ((const float*)Avk + (size_t)(bb*512+ii)*4096)
                                        : ((const float*)Avv + (size_t)(bb*512+ii-512)*4096);
        GLDS16(basef + k0 + sc*4, Asf + (it*256 + w*64)*4);
      }
    } else {
      #pragma unroll
      for (int it=0; it<MFR; ++it){
        int p16 = it*256 + t;
        int row = p16>>3; int ob = (p16&7)<<4;
        int sz = ob ^ ((row&7)<<4);
        const u16* src = A + (size_t)(m0+row)*K + k0 + (sz>>1);
        GLDS16(src, As + (it*256 + w*64)*8);
      }
    }
    #pragma unroll
    for (int it=0; it<NFR; ++it){
      int p16 = it*256 + t;
      int row = p16>>3; int ob = (p16&7)<<4;
      int sz = ob ^ ((row&7)<<4);
      const u16* src = BT + (size_t)(n0+row)*K + k0 + (sz>>1);
      GLDS16(src, Bs + (it*256 + w*64)*8);
    }
    __syncthreads();

    bf16v8 af[MFR][2], bfr[NFR][2];
    #pragma unroll
    for (int kk=0;kk<2;++kk){
      #pragma unroll
      for (int m=0;m<MFR;++m){
        int row = wr*(BM/2) + m*16 + l16;
        if (F32A && CONCAT){
          const char* ap = (const char*)Asf + row*256;
          int sw = (row&7)<<4;
          f32x4 a0 = *(const f32x4*)(ap + ((kk*128 + grp*32)      ^ sw));
          f32x4 a1 = *(const f32x4*)(ap + ((kk*128 + grp*32 + 16) ^ sw));
          bf16v8 av;
          #pragma unroll
          for (int j=0;j<4;++j){ av[j] = (__bf16)a0[j]; av[j+4] = (__bf16)a1[j]; }
          af[m][kk] = av;
        } else {
          int ob = (kk*64 + grp*16) ^ ((row&7)<<4);
          af[m][kk] = *(const bf16v8*)((const char*)As + row*128 + ob);
        }
      }
      #pragma unroll
      for (int n=0;n<NFR;++n){
        int row = wc*(BN/2) + n*16 + l16;
        int ob = (kk*64 + grp*16) ^ ((row&7)<<4);
        bfr[n][kk] = *(const bf16v8*)((const char*)Bs + row*128 + ob);
      }
    }
    #pragma unroll
    for (int kk=0;kk<2;++kk)
      #pragma unroll
      for (int m=0;m<MFR;++m)
        #pragma unroll
        for (int n=0;n<NFR;++n)
          acc[m][n] = mfma16(af[m][kk], bfr[n][kk], acc[m][n]);
    __syncthreads();
  }

  if (SPLITS > 1){
    #pragma unroll
    for (int m=0;m<MFR;++m)
      #pragma unroll
      for (int n=0;n<NFR;++n)
        #pragma unroll
        for (int r=0;r<4;++r){
          int row = m0 + wr*(BM/2) + m*16 + grp*4 + r;
          int col = n0 + wc*(BN/2) + n*16 + l16;
          Cf[(size_t)blockIdx.z*M*N + (size_t)row*N + col] = acc[m][n][r];
        }
  } else if (EPI == 4){
    const int kind = n0 >> 9;                       // 0=q, 1=k, 2=v
    if (kind < 2){
      const int hh = ((n0 & 511) + wc*(BN/2)) >> 6; // head 0..7
      #pragma unroll
      for (int m=0;m<MFR;++m){
        #pragma unroll
        for (int n=0;n<2;++n){
          int dp = n*16 + l16;                      // 0..31
          float invf = __expf(-(float)dp * 0.28782314f);  // 10000^(-dp/32)
          float b1 = bias[n0 + wc*(BN/2) + n*16 + l16];
          float b2 = bias[n0 + wc*(BN/2) + (n+2)*16 + l16];
          #pragma unroll
          for (int r=0;r<4;++r){
            int rowg = m0 + wr*(BM/2) + m*16 + grp*4 + r;
            int bb = rowg>>10, ii = rowg&1023;
            float x1 = acc[m][n][r]   + b1;
            float x2 = acc[m][n+2][r] + b2;
            float fr = (float)ii * invf;
            float sn, cs; __sincosf(fr, &sn, &cs);
            float r1 = x1*cs - x2*sn, r2 = x2*cs + x1*sn;
            if (kind == 0){
              u16* qd = Qhp + ((size_t)(bb*8+hh)*1024 + ii)*64;
              qd[dp]    = f2b(r1*0.125f);
              qd[dp+32] = f2b(r2*0.125f);
            } else {
              u16* kd = KEYSp + ((size_t)(bb*8+hh)*1536 + 512 + ii)*64;
              kd[dp]    = f2b(r1);
              kd[dp+32] = f2b(r2);
            }
          }
        }
      }
    } else {
      #pragma unroll
      for (int m=0;m<MFR;++m)
        #pragma unroll
        for (int n=0;n<NFR;++n)
          #pragma unroll
          for (int r=0;r<4;++r){
            int rowg = m0 + wr*(BM/2) + m*16 + grp*4 + r;
            int col = n0 + wc*(BN/2) + n*16 + l16;
            Cb[(size_t)rowg*N + col] = f2b(acc[m][n][r] + bias[col]);
          }
    }
  } else {
    #pragma unroll
    for (int m=0;m<MFR;++m){
      #pragma unroll
      for (int n=0;n<NFR;++n){
        #pragma unroll
        for (int r=0;r<4;++r){
          int row = m0 + wr*(BM/2) + m*16 + grp*4 + r;
          int col = n0 + wc*(BN/2) + n*16 + l16;
          size_t idx = (size_t)row*N + col;
          float v = acc[m][n][r] + bias[col];
          if (EPI == 0){
            Cb[idx] = f2b(v);
          } else if (EPI == 1){
            Cf[idx] = v + resid[idx];
          } else if (EPI == 2){
            v = 0.5f*v*(1.f + erff(v*0.70710678f));
            Cb[idx] = f2b(v);
          } else {
            Cf[idx] = v + addf[idx];
          }
        }
      }
    }
  }
}

// ---------------- split-K combine (+bias -> bf16 skv) + sk rows mirrored into KEYS ----------------
template<int SPLITS>
__global__ __launch_bounds__(256) void combine_k(const float* __restrict__ P, const float* __restrict__ bias,
                                                 u16* __restrict__ outb, u16* __restrict__ KEYSp,
                                                 int n8, int N){
  int i = blockIdx.x*256 + threadIdx.x;
  if (i >= n8) return;
  size_t base = (size_t)i*8;
  const size_t MN = (size_t)n8*8;
  float acc[8];
  {
    f32x4 a = *(const f32x4*)(P + base), b = *(const f32x4*)(P + base + 4);
    #pragma unroll
    for (int j=0;j<4;++j){ acc[j]=a[j]; acc[j+4]=b[j]; }
  }
  #pragma unroll
  for (int s=1;s<SPLITS;++s){
    f32x4 a = *(const f32x4*)(P + s*MN + base), b = *(const f32x4*)(P + s*MN + base + 4);
    #pragma unroll
    for (int j=0;j<4;++j){ acc[j]+=a[j]; acc[j+4]+=b[j]; }
  }
  int col0 = (int)(base % N);
  u16x8 o;
  #pragma unroll
  for (int j=0;j<8;++j) o[j] = f2b(acc[j] + bias[col0+j]);
  *(u16x8*)(outb + base) = o;
  int g = (int)(base >> 9);          // global row (N=512)
  int b = g >> 10, ii = g & 1023;
  if (ii < 512){
    *(u16x8*)(KEYSp + ((size_t)(b*8 + (col0>>6))*1536 + ii)*64 + (col0&63)) = o;
  }
}

// ---------------- build transposed values VT[bh][d][j] ----------------
__global__ __launch_bounds__(256) void build_vt(const u16* __restrict__ qkv, const u16* __restrict__ skv,
                                                u16* __restrict__ VT){
  __shared__ u16 tile[64][66];
  int blk = blockIdx.x;
  int bh = blk / 24, tt = blk % 24;
  int b = bh>>3, h = bh&7;
  int t = threadIdx.x;
  int jbase;
  if (tt < 16){
    int i0 = tt*64; jbase = 512 + i0;
    #pragma unroll
    for (int it=0; it<16; ++it){
      int idx = it*256+t; int r = idx>>6, c = idx&63;
      tile[r][c] = qkv[((size_t)b*1024 + i0 + r)*1536 + 1024 + h*64 + c];
    }
  } else {
    int j0 = (tt-16)*64; jbase = j0;
    #pragma unroll
    for (int it=0; it<16; ++it){
      int idx = it*256+t; int r = idx>>6, c = idx&63;
      tile[r][c] = skv[((size_t)b*1024 + 512 + j0 + r)*512 + h*64 + c];
    }
  }
  __syncthreads();
  #pragma unroll
  for (int it=0; it<16; ++it){
    int idx = it*256+t; int c = idx>>6, r = idx&63;
    VT[((size_t)bh*64 + c)*1536 + jbase + r] = tile[r][c];
  }
}

// ---------------- flash attention: interleaved balanced 2-way tile split ----------------
__global__ __launch_bounds__(256,4) void attn_k(const u16* __restrict__ Qh, const u16* __restrict__ KEYS,
                                                const u16* __restrict__ VT,
                                                float* __restrict__ Op, float2* __restrict__ Ml2){
  __shared__ alignas(16) u16 Ks[2][64*64];
  __shared__ alignas(16) u16 Vs[2][64*64];
  __shared__ alignas(16) u16 Pl[4][16*64];
  const int t = threadIdx.x, w = t>>6, l = t&63, grp = l>>4, l16 = l&15;
  const int blk = blockIdx.x;
  const int s = blk & 1, qg = (blk>>1) & 15, bh = blk>>5;
  const int i0 = qg*64 + w*16;
  int khi = qg*64 + 576; if (khi > 1536) khi = 1536;
  const int ntt = khi >> 6;
  const size_t prow = ((size_t)s*32 + bh)*1024;

  const u16* Qb = Qh + (size_t)bh*65536;
  const u16* Kb = KEYS + (size_t)bh*98304;
  const u16* Vb = VT + (size_t)bh*98304;
  u16* Pw = &Pl[w][0];
  const int swz = (l16&7)<<4;
  const int qlim = i0 + l16 + 512;

  bf16v8 qf[2];
  #pragma unroll
  for (int kk=0;kk<2;++kk)
    qf[kk] = *(const bf16v8*)(Qb + (size_t)(i0 + l16)*64 + kk*32 + grp*8);

  f32x4 Ot[4];
  #pragma unroll
  for (int n=0;n<4;++n) Ot[n] = f32x4{0.f,0.f,0.f,0.f};
  float mrun = -1e30f, lrun = 0.f;

  #pragma unroll
  for (int it=0; it<2; ++it){
    int p16 = it*256 + t; int row = p16>>3; int sb = ((p16&7)<<4) ^ ((row&7)<<4);
    GLDS16(Kb + (size_t)(s*64+row)*64 + (sb>>1), &Ks[0][0] + (it*256 + w*64)*8);
    GLDS16(Vb + (size_t)row*1536 + s*64 + (sb>>1), &Vs[0][0] + (it*256 + w*64)*8);
  }
  __syncthreads();

  int buf = 0;
  for (int tt = s; tt < ntt; tt += 2){
    const int j0 = tt*64;
    if (tt+2 < ntt){
      const int j1 = j0 + 128, nb = buf^1;
      #pragma unroll
      for (int it=0; it<2; ++it){
        int p16 = it*256 + t; int row = p16>>3; int sb = ((p16&7)<<4) ^ ((row&7)<<4);
        GLDS16(Kb + (size_t)(j1+row)*64 + (sb>>1), &Ks[nb][0] + (it*256 + w*64)*8);
        GLDS16(Vb + (size_t)row*1536 + j1 + (sb>>1), &Vs[nb][0] + (it*256 + w*64)*8);
      }
    }
    const char* Kt = (const char*)&Ks[buf][0];
    const char* Vt = (const char*)&Vs[buf][0];

    f32x4 St[4];
    #pragma unroll
    for (int n=0;n<4;++n) St[n] = f32x4{0.f,0.f,0.f,0.f};
    #pragma unroll
    for (int kk=0;kk<2;++kk)
      #pragma unroll
      for (int n=0;n<4;++n){
        int row = n*16 + l16;
        bf16v8 kf = *(const bf16v8*)(Kt + row*128 + ((kk*64 + grp*16) ^ swz));
        St[n] = mfma16(kf, qf[kk], St[n]);
      }
    const bool tail = (j0 + 63 > i0 + 512);
    float sv[4][4]; float m_loc = -1e30f;
    #pragma unroll
    for (int n=0;n<4;++n)
      #pragma unroll
      for (int r=0;r<4;++r){
        float x = St[n][r];
        if (tail && (j0 + n*16 + grp*4 + r > qlim)) x = -1e30f;
        sv[n][r] = x; m_loc = fmaxf(m_loc, x);
      }
    m_loc = fmaxf(m_loc, __shfl_xor(m_loc, 16, 64));
    m_loc = fmaxf(m_loc, __shfl_xor(m_loc, 32, 64));
    float mnew = fmaxf(mrun, m_loc);
    float alpha = __expf(mrun - mnew);
    float rs = 0.f;
    unsigned pk[8];
    #pragma unroll
    for (int n=0;n<4;++n)
      #pragma unroll
      for (int c2=0;c2<2;++c2){
        float p0 = __expf(sv[n][2*c2]   - mnew);
        float p1 = __expf(sv[n][2*c2+1] - mnew);
        rs += p0 + p1;
        pk[n*2+c2] = (unsigned)f2b(p0) | ((unsigned)f2b(p1) << 16);
      }
    rs += __shfl_xor(rs, 16, 64);
    rs += __shfl_xor(rs, 32, 64);
    lrun = lrun*alpha + rs;
    mrun = mnew;
    #pragma unroll
    for (int n=0;n<4;++n)
      #pragma unroll
      for (int r=0;r<4;++r) Ot[n][r] *= alpha;
    #pragma unroll
    for (int n=0;n<4;++n)
      #pragma unroll
      for (int c2=0;c2<2;++c2)
        *(unsigned*)((char*)Pw + l16*128 + ((n*32 + grp*8 + c2*4) ^ swz)) = pk[n*2+c2];
    bf16v8 pb0 = *(const bf16v8*)((const char*)Pw + l16*128 + ((grp*16)      ^ swz));
    bf16v8 pb1 = *(const bf16v8*)((const char*)Pw + l16*128 + ((64 + grp*16) ^ swz));
    #pragma unroll
    for (int n=0;n<4;++n){
      int row = n*16 + l16;
      bf16v8 vf0 = *(const bf16v8*)(Vt + row*128 + ((grp*16)      ^ swz));
      bf16v8 vf1 = *(const bf16v8*)(Vt + row*128 + ((64 + grp*16) ^ swz));
      Ot[n] = mfma16(vf0, pb0, Ot[n]);
      Ot[n] = mfma16(vf1, pb1, Ot[n]);
    }
    __syncthreads();
    buf ^= 1;
  }

  float* Tw = (float*)Pw;
  #pragma unroll
  for (int hf=0; hf<2; ++hf){
    #pragma unroll
    for (int nn=0; nn<2; ++nn)
      #pragma unroll
      for (int r=0; r<4; ++r)
        *(float*)((char*)Tw + l16*128 + ((((nn*16 + grp*4 + r)*4)) ^ swz)) = Ot[hf*2+nn][r];
    f32x4 v0 = *(const f32x4*)((const char*)Tw + l16*128 + ((grp*32)      ^ swz));
    f32x4 v1 = *(const f32x4*)((const char*)Tw + l16*128 + ((grp*32 + 16) ^ swz));
    float* dst = Op + (prow + i0 + l16)*64 + hf*32 + grp*8;
    *(f32x4*)dst = v0;
    *(f32x4*)(dst+4) = v1;
  }
  if (grp == 0) Ml2[prow + i0 + l16] = make_float2(mrun, lrun);
}

// ---------------- combine 2 split partials -> AO bf16 (512 threads: ALL 8 heads) ----------------
__global__ __launch_bounds__(512) void attn_combine(const float* __restrict__ Op, const float2* __restrict__ Ml2,
                                                    u16* __restrict__ AO){
  int bi = blockIdx.x;
  int b = bi>>10, i = bi&1023;
  int t = threadIdx.x; int h = t>>6, d = t&63;
  int bh = b*8 + h;
  float2 ml0 = Ml2[(size_t)bh*1024 + i];
  float2 ml1 = Ml2[((size_t)32 + bh)*1024 + i];
  float M = fmaxf(ml0.x, ml1.x);
  float a0 = (ml0.y > 0.f) ? __expf(ml0.x - M) : 0.f;
  float a1 = (ml1.y > 0.f) ? __expf(ml1.x - M) : 0.f;
  float denom = a0*ml0.y + a1*ml1.y;
  float o = 0.f;
  if (a0 > 0.f) o += a0 * Op[((size_t)bh*1024 + i)*64 + d];
  if (a1 > 0.f) o += a1 * Op[(((size_t)32 + bh)*1024 + i)*64 + d];
  AO[((size_t)b*1024 + i)*512 + h*64 + d] = f2b(o / denom);
}

// ---------------- launcher ----------------
extern "C" void kernel_launch(void* const* d_in, const int* in_sizes, int n_in,
                              void* d_out, int out_size, void* d_ws, size_t ws_size,
                              hipStream_t stream) {
  const float* planning = (const float*)d_in[0];
  const float* vk   = (const float*)d_in[1];
  const float* vv   = (const float*)d_in[2];
  const float* Wskv = (const float*)d_in[3];
  const float* bskv = (const float*)d_in[4];
  const float* Wqkv = (const float*)d_in[5];
  const float* bqkv = (const float*)d_in[6];
  const float* Wout = (const float*)d_in[7];
  const float* bout = (const float*)d_in[8];
  const float* Wff1 = (const float*)d_in[9];
  const float* bff1 = (const float*)d_in[10];
  const float* Wff2 = (const float*)d_in[11];
  const float* bff2 = (const float*)d_in[12];
  const float* g1   = (const float*)d_in[13];
  const float* g2   = (const float*)d_in[14];
  float* outp = (float*)d_out;

  char* w8 = (char*)d_ws;
  size_t off = 0;
  auto take = [&](size_t n)->char*{ char* p = w8 + off; off += (n + 255) & ~(size_t)255; return p; };
  u16* WTqkv   = (u16*)take((size_t)1536*512*2);
  u16* WTskv   = (u16*)take((size_t)512*4096*2);
  u16* WTout   = (u16*)take((size_t)512*512*2);
  u16* WTff1   = (u16*)take((size_t)512*512*2);
  u16* WTff2   = (u16*)take((size_t)512*512*2);
  u16* normed1 = (u16*)take((size_t)4096*512*2);
  u16* qkv     = (u16*)take((size_t)4096*1536*2);
  u16* skv     = (u16*)take((size_t)4096*512*2);
  u16* Qh      = (u16*)take((size_t)32*1024*64*2);
  u16* KEYS    = (u16*)take((size_t)32*1536*64*2);
  u16* VT      = (u16*)take((size_t)32*64*1536*2);
  u16* AO      = (u16*)take((size_t)4096*512*2);
  float* all_out = (float*)take((size_t)4096*512*4);
  u16* normed2 = (u16*)take((size_t)4096*512*2);
  u16* h1      = (u16*)take((size_t)4096*512*2);
  float* Op    = (float*)take((size_t)2*32*1024*64*4);
  float2* Ml2  = (float2*)take((size_t)2*32*1024*8);
  float* Pd    = (float*)take((size_t)8*4096*512*4);   // split-K partials (skv, 8 splits)
  (void)in_sizes; (void)n_in; (void)out_size; (void)ws_size;

  prep_k<<<dim3(1920), 256, 0, stream>>>(Wqkv, Wskv, Wout, Wff1, Wff2,
                                         WTqkv, WTskv, WTout, WTff1, WTff2,
                                         planning, g1, normed1);

  gemm_k<64,128,4,false,false,1,4><<<dim3(64,12), 256, 0, stream>>>(normed1,nullptr,nullptr, WTqkv, bqkv, qkv, nullptr, nullptr, nullptr, Qh, KEYS, 4096, 1536, 512);
  gemm_k<128,128,0,true,true,8,3><<<dim3(32,4,8), 256, 0, stream>>>(nullptr, vk, vv,        WTskv, bskv, nullptr, Pd, nullptr, nullptr, nullptr, nullptr, 4096, 512, 4096);
  combine_k<8><<<dim3(1024), 256, 0, stream>>>(Pd, bskv, skv, KEYS, 262144, 512);

  build_vt<<<dim3(768), 256, 0, stream>>>(qkv, skv, VT);

  attn_k<<<dim3(1024), 256, 0, stream>>>(Qh, KEYS, VT, Op, Ml2);
  attn_combine<<<dim3(4096), 512, 0, stream>>>(Op, Ml2, AO);

  gemm_k<64,64,1,false,false,1,4><<<dim3(64,8), 256, 0, stream>>>(AO, nullptr,nullptr, WTout, bout, nullptr, all_out, planning, nullptr, nullptr, nullptr, 4096, 512, 512);
  rmsn_k<<<dim3(1024), 256, 0, stream>>>(all_out, g2, normed2);
  gemm_k<64,64,2,false,false,1,4><<<dim3(64,8), 256, 0, stream>>>(normed2, nullptr,nullptr, WTff1, bff1, h1, nullptr, nullptr, nullptr, nullptr, nullptr, 4096, 512, 512);
  gemm_k<64,64,3,false,false,1,4><<<dim3(64,8), 256, 0, stream>>>(h1, nullptr,nullptr, WTff2, bff2, nullptr, outp, nullptr, all_out, nullptr, nullptr, 4096, 512, 512);
}

// Round 21
// 135.628 us; speedup vs baseline: 1.1064x; 1.1064x over previous
//
#include <hip/hip_runtime.h>
#include <math.h>

typedef unsigned short u16;
typedef unsigned short u16x8 __attribute__((ext_vector_type(8)));
typedef __bf16 bf16v8 __attribute__((ext_vector_type(8)));
typedef float f32x4 __attribute__((ext_vector_type(4)));

static __device__ __forceinline__ float b2f(u16 u){ union{unsigned v; float f;} x; x.v=((unsigned)u)<<16; return x.f; }
static __device__ __forceinline__ u16 f2b(float f){ union{float f; unsigned v;} x; x.f=f; unsigned r=x.v+0x7fffu+((x.v>>16)&1u); return (u16)(r>>16); }
static __device__ __forceinline__ f32x4 mfma16(bf16v8 a, bf16v8 b, f32x4 c){
  return __builtin_amdgcn_mfma_f32_16x16x32_bf16(a,b,c,0,0,0);
}
#define GLDS16(g,l) __builtin_amdgcn_global_load_lds((const __attribute__((address_space(1))) unsigned*)(g), (__attribute__((address_space(3))) unsigned*)(l), 16, 0, 0)

// ---------------- fused prep: 5 weight transposes (blk<896) + rmsnorm1 ----------------
__global__ __launch_bounds__(256) void prep_k(
    const float* __restrict__ Wqkv, const float* __restrict__ Wskv, const float* __restrict__ Wout,
    const float* __restrict__ Wff1, const float* __restrict__ Wff2,
    u16* __restrict__ Tqkv, u16* __restrict__ Tskv, u16* __restrict__ Tout,
    u16* __restrict__ Tff1, u16* __restrict__ Tff2,
    const float* __restrict__ x, const float* __restrict__ g, u16* __restrict__ o){
  __shared__ u16 tile[64][66];
  int blk = blockIdx.x, t = threadIdx.x;
  if (blk < 896){
    const float* in; u16* out; int R, C, lb;
    if (blk < 192){ in=Wqkv; out=Tqkv; R=512;  C=1536; lb=blk; }
    else if (blk < 704){ in=Wskv; out=Tskv; R=4096; C=512; lb=blk-192; }
    else if (blk < 768){ in=Wout; out=Tout; R=512; C=512; lb=blk-704; }
    else if (blk < 832){ in=Wff1; out=Tff1; R=512; C=512; lb=blk-768; }
    else { in=Wff2; out=Tff2; R=512; C=512; lb=blk-832; }
    int ct = C >> 6;
    int bx = lb % ct, by = lb / ct;
    #pragma unroll
    for (int it=0; it<16; ++it){
      int idx = it*256 + t; int r = idx>>6, c = idx&63;
      tile[r][c] = f2b(in[(size_t)(by*64+r)*C + bx*64 + c]);
    }
    __syncthreads();
    #pragma unroll
    for (int it=0; it<16; ++it){
      int idx = it*256 + t; int c = idx>>6, r = idx&63;
      out[(size_t)(bx*64+c)*R + by*64 + r] = tile[r][c];
    }
    return;
  }
  int w = t>>6, l = t&63;
  size_t row = (size_t)(blk-896)*4 + w;
  const float* xr = x + row*512 + l*8;
  f32x4 a = *(const f32x4*)xr, b = *(const f32x4*)(xr+4);
  float f[8]; float ss = 0.f;
  #pragma unroll
  for (int j=0;j<4;++j){ f[j]=a[j]; f[j+4]=b[j]; }
  #pragma unroll
  for (int j=0;j<8;++j) ss += f[j]*f[j];
  #pragma unroll
  for (int m=1;m<64;m<<=1) ss += __shfl_xor(ss, m, 64);
  float inv = rsqrtf(ss*(1.0f/512.f) + 1e-6f);
  f32x4 ga = *(const f32x4*)(g + l*8), gb = *(const f32x4*)(g + l*8 + 4);
  u16x8 ov;
  #pragma unroll
  for (int j=0;j<4;++j){ ov[j] = f2b(f[j]*inv*(1.f + ga[j])); ov[j+4] = f2b(f[j+4]*inv*(1.f + gb[j])); }
  *(u16x8*)(o + row*512 + l*8) = ov;
}

// ---------------- rmsnorm: f32 in, f32 gamma, bf16 out ----------------
__global__ __launch_bounds__(256) void rmsn_k(const float* __restrict__ x, const float* __restrict__ g, u16* __restrict__ o){
  int w = threadIdx.x>>6, l = threadIdx.x&63;
  size_t row = (size_t)blockIdx.x*4 + w;
  const float* xr = x + row*512 + l*8;
  f32x4 a = *(const f32x4*)xr, b = *(const f32x4*)(xr+4);
  float f[8]; float ss = 0.f;
  #pragma unroll
  for (int j=0;j<4;++j){ f[j]=a[j]; f[j+4]=b[j]; }
  #pragma unroll
  for (int j=0;j<8;++j) ss += f[j]*f[j];
  #pragma unroll
  for (int m=1;m<64;m<<=1) ss += __shfl_xor(ss, m, 64);
  float inv = rsqrtf(ss*(1.0f/512.f) + 1e-6f);
  f32x4 ga = *(const f32x4*)(g + l*8), gb = *(const f32x4*)(g + l*8 + 4);
  u16x8 ov;
  #pragma unroll
  for (int j=0;j<4;++j){ ov[j] = f2b(f[j]*inv*(1.f + ga[j])); ov[j+4] = f2b(f[j+4]*inv*(1.f + gb[j])); }
  *(u16x8*)(o + row*512 + l*8) = ov;
}

// ---------------- GEMM: C[M,N] = A[M,K] @ BT[N,K]^T (+epilogue or split-K partial) ----------------
// F32A (with CONCAT): A is f32 (vk/vv), staged via global_load_lds (f32 tile in LDS),
//   converted bf16 at fragment read via (__bf16) casts.
// EPI 0: bias->bf16 Cb ; 1: bias+resid->f32 Cf ; 2: bias+gelu->bf16 Cb ; 3: bias+addf->f32 Cf
// EPI 4: fused qkv epilogue (q/k: bias+RoPE -> Qhp/KEYSp; v -> Cb).
template<int BM, int BN, int EPI, bool CONCAT, bool F32A, int SPLITS, int WAVES>
__global__ __launch_bounds__(256,WAVES) void gemm_k(
  const u16* __restrict__ A, const void* __restrict__ Avk, const void* __restrict__ Avv,
  const u16* __restrict__ BT, const float* __restrict__ bias,
  u16* __restrict__ Cb, float* __restrict__ Cf,
  const float* __restrict__ resid, const float* __restrict__ addf,
  u16* __restrict__ Qhp, u16* __restrict__ KEYSp,
  int M, int N, int K)
{
  constexpr int BK = 64;
  constexpr int MFR = BM/32, NFR = BN/32;
  constexpr int ABYTES = F32A ? BM*BK*4 : BM*BK*2;
  __shared__ alignas(16) char sm[ABYTES + BN*BK*2];
  float* Asf = (float*)sm;
  u16* As = (u16*)sm;
  u16* Bs = (u16*)(sm + ABYTES);
  const int t = threadIdx.x, w = t>>6, l = t&63, grp = l>>4, l16 = l&15;
  const int wr = w>>1, wc = w&1;
  const int m0 = blockIdx.x*BM, n0 = blockIdx.y*BN;
  const int kchunk = K/SPLITS, kbeg = blockIdx.z*kchunk, kend = kbeg + kchunk;

  f32x4 acc[MFR][NFR];
  #pragma unroll
  for (int m=0;m<MFR;++m)
    #pragma unroll
    for (int n=0;n<NFR;++n) acc[m][n] = f32x4{0.f,0.f,0.f,0.f};

  for (int k0 = kbeg; k0 < kend; k0 += BK){
    if (F32A && CONCAT){
      #pragma unroll
      for (int it=0; it<BM/16; ++it){
        int p = it*256 + t;
        int row = p>>4, c16 = p&15;
        int sc = c16 ^ (row & 7);
        int gg = m0+row, bb = gg>>10, ii = gg&1023;
        const float* basef = (ii < 512) ? ((const float*)Avk + (size_t)(bb*512+ii)*4096)
                                        : ((const float*)Avv + (size_t)(bb*512+ii-512)*4096);
        GLDS16(basef + k0 + sc*4, Asf + (it*256 + w*64)*4);
      }
    } else {
      #pragma unroll
      for (int it=0; it<MFR; ++it){
        int p16 = it*256 + t;
        int row = p16>>3; int ob = (p16&7)<<4;
        int sz = ob ^ ((row&7)<<4);
        const u16* src = A + (size_t)(m0+row)*K + k0 + (sz>>1);
        GLDS16(src, As + (it*256 + w*64)*8);
      }
    }
    #pragma unroll
    for (int it=0; it<NFR; ++it){
      int p16 = it*256 + t;
      int row = p16>>3; int ob = (p16&7)<<4;
      int sz = ob ^ ((row&7)<<4);
      const u16* src = BT + (size_t)(n0+row)*K + k0 + (sz>>1);
      GLDS16(src, Bs + (it*256 + w*64)*8);
    }
    __syncthreads();

    bf16v8 af[MFR][2], bfr[NFR][2];
    #pragma unroll
    for (int kk=0;kk<2;++kk){
      #pragma unroll
      for (int m=0;m<MFR;++m){
        int row = wr*(BM/2) + m*16 + l16;
        if (F32A && CONCAT){
          const char* ap = (const char*)Asf + row*256;
          int sw = (row&7)<<4;
          f32x4 a0 = *(const f32x4*)(ap + ((kk*128 + grp*32)      ^ sw));
          f32x4 a1 = *(const f32x4*)(ap + ((kk*128 + grp*32 + 16) ^ sw));
          bf16v8 av;
          #pragma unroll
          for (int j=0;j<4;++j){ av[j] = (__bf16)a0[j]; av[j+4] = (__bf16)a1[j]; }
          af[m][kk] = av;
        } else {
          int ob = (kk*64 + grp*16) ^ ((row&7)<<4);
          af[m][kk] = *(const bf16v8*)((const char*)As + row*128 + ob);
        }
      }
      #pragma unroll
      for (int n=0;n<NFR;++n){
        int row = wc*(BN/2) + n*16 + l16;
        int ob = (kk*64 + grp*16) ^ ((row&7)<<4);
        bfr[n][kk] = *(const bf16v8*)((const char*)Bs + row*128 + ob);
      }
    }
    #pragma unroll
    for (int kk=0;kk<2;++kk)
      #pragma unroll
      for (int m=0;m<MFR;++m)
        #pragma unroll
        for (int n=0;n<NFR;++n)
          acc[m][n] = mfma16(af[m][kk], bfr[n][kk], acc[m][n]);
    __syncthreads();
  }

  if (SPLITS > 1){
    #pragma unroll
    for (int m=0;m<MFR;++m)
      #pragma unroll
      for (int n=0;n<NFR;++n)
        #pragma unroll
        for (int r=0;r<4;++r){
          int row = m0 + wr*(BM/2) + m*16 + grp*4 + r;
          int col = n0 + wc*(BN/2) + n*16 + l16;
          Cf[(size_t)blockIdx.z*M*N + (size_t)row*N + col] = acc[m][n][r];
        }
  } else if (EPI == 4){
    const int kind = n0 >> 9;                       // 0=q, 1=k, 2=v
    if (kind < 2){
      const int hh = ((n0 & 511) + wc*(BN/2)) >> 6; // head 0..7
      #pragma unroll
      for (int m=0;m<MFR;++m){
        #pragma unroll
        for (int n=0;n<2;++n){
          int dp = n*16 + l16;                      // 0..31
          float invf = __expf(-(float)dp * 0.28782314f);  // 10000^(-dp/32)
          float b1 = bias[n0 + wc*(BN/2) + n*16 + l16];
          float b2 = bias[n0 + wc*(BN/2) + (n+2)*16 + l16];
          #pragma unroll
          for (int r=0;r<4;++r){
            int rowg = m0 + wr*(BM/2) + m*16 + grp*4 + r;
            int bb = rowg>>10, ii = rowg&1023;
            float x1 = acc[m][n][r]   + b1;
            float x2 = acc[m][n+2][r] + b2;
            float fr = (float)ii * invf;
            float sn, cs; __sincosf(fr, &sn, &cs);
            float r1 = x1*cs - x2*sn, r2 = x2*cs + x1*sn;
            if (kind == 0){
              u16* qd = Qhp + ((size_t)(bb*8+hh)*1024 + ii)*64;
              qd[dp]    = f2b(r1*0.125f);
              qd[dp+32] = f2b(r2*0.125f);
            } else {
              u16* kd = KEYSp + ((size_t)(bb*8+hh)*1536 + 512 + ii)*64;
              kd[dp]    = f2b(r1);
              kd[dp+32] = f2b(r2);
            }
          }
        }
      }
    } else {
      #pragma unroll
      for (int m=0;m<MFR;++m)
        #pragma unroll
        for (int n=0;n<NFR;++n)
          #pragma unroll
          for (int r=0;r<4;++r){
            int rowg = m0 + wr*(BM/2) + m*16 + grp*4 + r;
            int col = n0 + wc*(BN/2) + n*16 + l16;
            Cb[(size_t)rowg*N + col] = f2b(acc[m][n][r] + bias[col]);
          }
    }
  } else {
    #pragma unroll
    for (int m=0;m<MFR;++m){
      #pragma unroll
      for (int n=0;n<NFR;++n){
        #pragma unroll
        for (int r=0;r<4;++r){
          int row = m0 + wr*(BM/2) + m*16 + grp*4 + r;
          int col = n0 + wc*(BN/2) + n*16 + l16;
          size_t idx = (size_t)row*N + col;
          float v = acc[m][n][r] + bias[col];
          if (EPI == 0){
            Cb[idx] = f2b(v);
          } else if (EPI == 1){
            Cf[idx] = v + resid[idx];
          } else if (EPI == 2){
            v = 0.5f*v*(1.f + erff(v*0.70710678f));
            Cb[idx] = f2b(v);
          } else {
            Cf[idx] = v + addf[idx];
          }
        }
      }
    }
  }
}

// ---------------- split-K combine (+bias -> bf16 skv) + sk rows mirrored into KEYS ----------------
template<int SPLITS>
__global__ __launch_bounds__(256) void combine_k(const float* __restrict__ P, const float* __restrict__ bias,
                                                 u16* __restrict__ outb, u16* __restrict__ KEYSp,
                                                 int n8, int N){
  int i = blockIdx.x*256 + threadIdx.x;
  if (i >= n8) return;
  size_t base = (size_t)i*8;
  const size_t MN = (size_t)n8*8;
  float acc[8];
  {
    f32x4 a = *(const f32x4*)(P + base), b = *(const f32x4*)(P + base + 4);
    #pragma unroll
    for (int j=0;j<4;++j){ acc[j]=a[j]; acc[j+4]=b[j]; }
  }
  #pragma unroll
  for (int s=1;s<SPLITS;++s){
    f32x4 a = *(const f32x4*)(P + s*MN + base), b = *(const f32x4*)(P + s*MN + base + 4);
    #pragma unroll
    for (int j=0;j<4;++j){ acc[j]+=a[j]; acc[j+4]+=b[j]; }
  }
  int col0 = (int)(base % N);
  u16x8 o;
  #pragma unroll
  for (int j=0;j<8;++j) o[j] = f2b(acc[j] + bias[col0+j]);
  *(u16x8*)(outb + base) = o;
  int g = (int)(base >> 9);          // global row (N=512)
  int b = g >> 10, ii = g & 1023;
  if (ii < 512){
    *(u16x8*)(KEYSp + ((size_t)(b*8 + (col0>>6))*1536 + ii)*64 + (col0&63)) = o;
  }
}

// ---------------- build transposed values VT[bh][d][j] ----------------
__global__ __launch_bounds__(256) void build_vt(const u16* __restrict__ qkv, const u16* __restrict__ skv,
                                                u16* __restrict__ VT){
  __shared__ u16 tile[64][66];
  int blk = blockIdx.x;
  int bh = blk / 24, tt = blk % 24;
  int b = bh>>3, h = bh&7;
  int t = threadIdx.x;
  int jbase;
  if (tt < 16){
    int i0 = tt*64; jbase = 512 + i0;
    #pragma unroll
    for (int it=0; it<16; ++it){
      int idx = it*256+t; int r = idx>>6, c = idx&63;
      tile[r][c] = qkv[((size_t)b*1024 + i0 + r)*1536 + 1024 + h*64 + c];
    }
  } else {
    int j0 = (tt-16)*64; jbase = j0;
    #pragma unroll
    for (int it=0; it<16; ++it){
      int idx = it*256+t; int r = idx>>6, c = idx&63;
      tile[r][c] = skv[((size_t)b*1024 + 512 + j0 + r)*512 + h*64 + c];
    }
  }
  __syncthreads();
  #pragma unroll
  for (int it=0; it<16; ++it){
    int idx = it*256+t; int c = idx>>6, r = idx&63;
    VT[((size_t)bh*64 + c)*1536 + jbase + r] = tile[r][c];
  }
}

// ---------------- flash attention: interleaved balanced 2-way tile split ----------------
__global__ __launch_bounds__(256,4) void attn_k(const u16* __restrict__ Qh, const u16* __restrict__ KEYS,
                                                const u16* __restrict__ VT,
                                                float* __restrict__ Op, float2* __restrict__ Ml2){
  __shared__ alignas(16) u16 Ks[2][64*64];
  __shared__ alignas(16) u16 Vs[2][64*64];
  __shared__ alignas(16) u16 Pl[4][16*64];
  const int t = threadIdx.x, w = t>>6, l = t&63, grp = l>>4, l16 = l&15;
  const int blk = blockIdx.x;
  const int s = blk & 1, qg = (blk>>1) & 15, bh = blk>>5;
  const int i0 = qg*64 + w*16;
  int khi = qg*64 + 576; if (khi > 1536) khi = 1536;
  const int ntt = khi >> 6;
  const size_t prow = ((size_t)s*32 + bh)*1024;

  const u16* Qb = Qh + (size_t)bh*65536;
  const u16* Kb = KEYS + (size_t)bh*98304;
  const u16* Vb = VT + (size_t)bh*98304;
  u16* Pw = &Pl[w][0];
  const int swz = (l16&7)<<4;
  const int qlim = i0 + l16 + 512;

  bf16v8 qf[2];
  #pragma unroll
  for (int kk=0;kk<2;++kk)
    qf[kk] = *(const bf16v8*)(Qb + (size_t)(i0 + l16)*64 + kk*32 + grp*8);

  f32x4 Ot[4];
  #pragma unroll
  for (int n=0;n<4;++n) Ot[n] = f32x4{0.f,0.f,0.f,0.f};
  float mrun = -1e30f, lrun = 0.f;

  #pragma unroll
  for (int it=0; it<2; ++it){
    int p16 = it*256 + t; int row = p16>>3; int sb = ((p16&7)<<4) ^ ((row&7)<<4);
    GLDS16(Kb + (size_t)(s*64+row)*64 + (sb>>1), &Ks[0][0] + (it*256 + w*64)*8);
    GLDS16(Vb + (size_t)row*1536 + s*64 + (sb>>1), &Vs[0][0] + (it*256 + w*64)*8);
  }
  __syncthreads();

  int buf = 0;
  for (int tt = s; tt < ntt; tt += 2){
    const int j0 = tt*64;
    if (tt+2 < ntt){
      const int j1 = j0 + 128, nb = buf^1;
      #pragma unroll
      for (int it=0; it<2; ++it){
        int p16 = it*256 + t; int row = p16>>3; int sb = ((p16&7)<<4) ^ ((row&7)<<4);
        GLDS16(Kb + (size_t)(j1+row)*64 + (sb>>1), &Ks[nb][0] + (it*256 + w*64)*8);
        GLDS16(Vb + (size_t)row*1536 + j1 + (sb>>1), &Vs[nb][0] + (it*256 + w*64)*8);
      }
    }
    const char* Kt = (const char*)&Ks[buf][0];
    const char* Vt = (const char*)&Vs[buf][0];

    f32x4 St[4];
    #pragma unroll
    for (int n=0;n<4;++n) St[n] = f32x4{0.f,0.f,0.f,0.f};
    #pragma unroll
    for (int kk=0;kk<2;++kk)
      #pragma unroll
      for (int n=0;n<4;++n){
        int row = n*16 + l16;
        bf16v8 kf = *(const bf16v8*)(Kt + row*128 + ((kk*64 + grp*16) ^ swz));
        St[n] = mfma16(kf, qf[kk], St[n]);
      }
    const bool tail = (j0 + 63 > i0 + 512);
    float sv[4][4]; float m_loc = -1e30f;
    #pragma unroll
    for (int n=0;n<4;++n)
      #pragma unroll
      for (int r=0;r<4;++r){
        float x = St[n][r];
        if (tail && (j0 + n*16 + grp*4 + r > qlim)) x = -1e30f;
        sv[n][r] = x; m_loc = fmaxf(m_loc, x);
      }
    m_loc = fmaxf(m_loc, __shfl_xor(m_loc, 16, 64));
    m_loc = fmaxf(m_loc, __shfl_xor(m_loc, 32, 64));
    float mnew = fmaxf(mrun, m_loc);
    float alpha = __expf(mrun - mnew);
    float rs = 0.f;
    unsigned pk[8];
    #pragma unroll
    for (int n=0;n<4;++n)
      #pragma unroll
      for (int c2=0;c2<2;++c2){
        float p0 = __expf(sv[n][2*c2]   - mnew);
        float p1 = __expf(sv[n][2*c2+1] - mnew);
        rs += p0 + p1;
        pk[n*2+c2] = (unsigned)f2b(p0) | ((unsigned)f2b(p1) << 16);
      }
    rs += __shfl_xor(rs, 16, 64);
    rs += __shfl_xor(rs, 32, 64);
    lrun = lrun*alpha + rs;
    mrun = mnew;
    #pragma unroll
    for (int n=0;n<4;++n)
      #pragma unroll
      for (int r=0;r<4;++r) Ot[n][r] *= alpha;
    #pragma unroll
    for (int n=0;n<4;++n)
      #pragma unroll
      for (int c2=0;c2<2;++c2)
        *(unsigned*)((char*)Pw + l16*128 + ((n*32 + grp*8 + c2*4) ^ swz)) = pk[n*2+c2];
    bf16v8 pb0 = *(const bf16v8*)((const char*)Pw + l16*128 + ((grp*16)      ^ swz));
    bf16v8 pb1 = *(const bf16v8*)((const char*)Pw + l16*128 + ((64 + grp*16) ^ swz));
    #pragma unroll
    for (int n=0;n<4;++n){
      int row = n*16 + l16;
      bf16v8 vf0 = *(const bf16v8*)(Vt + row*128 + ((grp*16)      ^ swz));
      bf16v8 vf1 = *(const bf16v8*)(Vt + row*128 + ((64 + grp*16) ^ swz));
      Ot[n] = mfma16(vf0, pb0, Ot[n]);
      Ot[n] = mfma16(vf1, pb1, Ot[n]);
    }
    __syncthreads();
    buf ^= 1;
  }

  float* Tw = (float*)Pw;
  #pragma unroll
  for (int hf=0; hf<2; ++hf){
    #pragma unroll
    for (int nn=0; nn<2; ++nn)
      #pragma unroll
      for (int r=0; r<4; ++r)
        *(float*)((char*)Tw + l16*128 + ((((nn*16 + grp*4 + r)*4)) ^ swz)) = Ot[hf*2+nn][r];
    f32x4 v0 = *(const f32x4*)((const char*)Tw + l16*128 + ((grp*32)      ^ swz));
    f32x4 v1 = *(const f32x4*)((const char*)Tw + l16*128 + ((grp*32 + 16) ^ swz));
    float* dst = Op + (prow + i0 + l16)*64 + hf*32 + grp*8;
    *(f32x4*)dst = v0;
    *(f32x4*)(dst+4) = v1;
  }
  if (grp == 0) Ml2[prow + i0 + l16] = make_float2(mrun, lrun);
}

// ---------------- combine 2 split partials -> AO bf16 (512 threads: ALL 8 heads) ----------------
__global__ __launch_bounds__(512) void attn_combine(const float* __restrict__ Op, const float2* __restrict__ Ml2,
                                                    u16* __restrict__ AO){
  int bi = blockIdx.x;
  int b = bi>>10, i = bi&1023;
  int t = threadIdx.x; int h = t>>6, d = t&63;
  int bh = b*8 + h;
  float2 ml0 = Ml2[(size_t)bh*1024 + i];
  float2 ml1 = Ml2[((size_t)32 + bh)*1024 + i];
  float M = fmaxf(ml0.x, ml1.x);
  float a0 = (ml0.y > 0.f) ? __expf(ml0.x - M) : 0.f;
  float a1 = (ml1.y > 0.f) ? __expf(ml1.x - M) : 0.f;
  float denom = a0*ml0.y + a1*ml1.y;
  float o = 0.f;
  if (a0 > 0.f) o += a0 * Op[((size_t)bh*1024 + i)*64 + d];
  if (a1 > 0.f) o += a1 * Op[(((size_t)32 + bh)*1024 + i)*64 + d];
  AO[((size_t)b*1024 + i)*512 + h*64 + d] = f2b(o / denom);
}

// ---------------- launcher ----------------
extern "C" void kernel_launch(void* const* d_in, const int* in_sizes, int n_in,
                              void* d_out, int out_size, void* d_ws, size_t ws_size,
                              hipStream_t stream) {
  const float* planning = (const float*)d_in[0];
  const float* vk   = (const float*)d_in[1];
  const float* vv   = (const float*)d_in[2];
  const float* Wskv = (const float*)d_in[3];
  const float* bskv = (const float*)d_in[4];
  const float* Wqkv = (const float*)d_in[5];
  const float* bqkv = (const float*)d_in[6];
  const float* Wout = (const float*)d_in[7];
  const float* bout = (const float*)d_in[8];
  const float* Wff1 = (const float*)d_in[9];
  const float* bff1 = (const float*)d_in[10];
  const float* Wff2 = (const float*)d_in[11];
  const float* bff2 = (const float*)d_in[12];
  const float* g1   = (const float*)d_in[13];
  const float* g2   = (const float*)d_in[14];
  float* outp = (float*)d_out;

  char* w8 = (char*)d_ws;
  size_t off = 0;
  auto take = [&](size_t n)->char*{ char* p = w8 + off; off += (n + 255) & ~(size_t)255; return p; };
  u16* WTqkv   = (u16*)take((size_t)1536*512*2);
  u16* WTskv   = (u16*)take((size_t)512*4096*2);
  u16* WTout   = (u16*)take((size_t)512*512*2);
  u16* WTff1   = (u16*)take((size_t)512*512*2);
  u16* WTff2   = (u16*)take((size_t)512*512*2);
  u16* normed1 = (u16*)take((size_t)4096*512*2);
  u16* qkv     = (u16*)take((size_t)4096*1536*2);
  u16* skv     = (u16*)take((size_t)4096*512*2);
  u16* Qh      = (u16*)take((size_t)32*1024*64*2);
  u16* KEYS    = (u16*)take((size_t)32*1536*64*2);
  u16* VT      = (u16*)take((size_t)32*64*1536*2);
  u16* AO      = (u16*)take((size_t)4096*512*2);
  float* all_out = (float*)take((size_t)4096*512*4);
  u16* normed2 = (u16*)take((size_t)4096*512*2);
  u16* h1      = (u16*)take((size_t)4096*512*2);
  float* Op    = (float*)take((size_t)2*32*1024*64*4);
  float2* Ml2  = (float2*)take((size_t)2*32*1024*8);
  float* Pd    = (float*)take((size_t)4*4096*512*4);   // split-K partials (skv only)
  (void)in_sizes; (void)n_in; (void)out_size; (void)ws_size;

  prep_k<<<dim3(1920), 256, 0, stream>>>(Wqkv, Wskv, Wout, Wff1, Wff2,
                                         WTqkv, WTskv, WTout, WTff1, WTff2,
                                         planning, g1, normed1);

  gemm_k<64,128,4,false,false,1,4><<<dim3(64,12), 256, 0, stream>>>(normed1,nullptr,nullptr, WTqkv, bqkv, qkv, nullptr, nullptr, nullptr, Qh, KEYS, 4096, 1536, 512);
  gemm_k<128,128,0,true,true,4,2><<<dim3(32,4,4), 256, 0, stream>>>(nullptr, vk, vv,        WTskv, bskv, nullptr, Pd, nullptr, nullptr, nullptr, nullptr, 4096, 512, 4096);
  combine_k<4><<<dim3(1024), 256, 0, stream>>>(Pd, bskv, skv, KEYS, 262144, 512);

  build_vt<<<dim3(768), 256, 0, stream>>>(qkv, skv, VT);

  attn_k<<<dim3(1024), 256, 0, stream>>>(Qh, KEYS, VT, Op, Ml2);
  attn_combine<<<dim3(4096), 512, 0, stream>>>(Op, Ml2, AO);

  gemm_k<64,64,1,false,false,1,4><<<dim3(64,8), 256, 0, stream>>>(AO, nullptr,nullptr, WTout, bout, nullptr, all_out, planning, nullptr, nullptr, nullptr, 4096, 512, 512);
  rmsn_k<<<dim3(1024), 256, 0, stream>>>(all_out, g2, normed2);
  gemm_k<64,64,2,false,false,1,4><<<dim3(64,8), 256, 0, stream>>>(normed2, nullptr,nullptr, WTff1, bff1, h1, nullptr, nullptr, nullptr, nullptr, nullptr, 4096, 512, 512);
  gemm_k<64,64,3,false,false,1,4><<<dim3(64,8), 256, 0, stream>>>(h1, nullptr,nullptr, WTff2, bff2, nullptr, outp, nullptr, all_out, nullptr, nullptr, 4096, 512, 512);
}